// Round 1
// baseline (916.850 us; speedup 1.0000x reference)
//
#include <hip/hip_runtime.h>
#include <hip/hip_bf16.h>

// Problem constants (B=64, S=2048, H=512, 2H=1024)
#define BATCH 64
#define SEQ   2048
#define HDIM  512
#define K2H   1024
#define MROWS (BATCH * SEQ)   // 131072

typedef __bf16 bf16_t;
using bf16x8  = __attribute__((ext_vector_type(8))) __bf16;
using bf16x4  = __attribute__((ext_vector_type(4))) __bf16;
using floatx4 = __attribute__((ext_vector_type(4))) float;

// ---------------------------------------------------------------------------
// K0a: dec_feat[b][h] = decoder_state[b] @ W_s[:,h] + b_s[h]   (64x512)
// ---------------------------------------------------------------------------
__global__ void dec_feat_kernel(const float* __restrict__ dec,
                                const float* __restrict__ Ws,
                                const float* __restrict__ bs,
                                float* __restrict__ out) {
    const int b = blockIdx.x;
    const int h = threadIdx.x;            // 512 threads
    const float* dr = dec + b * HDIM;
    float acc = bs[h];
#pragma unroll 8
    for (int k = 0; k < HDIM; ++k)
        acc += dr[k] * Ws[k * HDIM + h];  // coalesced over h; dr[k] uniform
    out[b * HDIM + h] = acc;
}

// ---------------------------------------------------------------------------
// K0b: pack W_h (1024x512 fp32, row-major [k][n]) into bf16 MFMA-B-fragment
// layout: Wt[((kk*32 + nt)*64 + lane)*8 + j] = Wh[(kk*32 + q*8 + j)][nt*16+r]
// where lane = q*16+r. A wave's B-frag load is then lane-contiguous 16B.
// ---------------------------------------------------------------------------
__global__ void pack_wh_kernel(const float* __restrict__ Wh,
                               bf16_t* __restrict__ Wt) {
    const int id = blockIdx.x * 256 + threadIdx.x;   // 524288 total
    const int k = id >> 9;        // 0..1023
    const int n = id & 511;       // 0..511
    const int kk = k >> 5;        // 32-wide K step
    const int q  = (k >> 3) & 3;  // quad
    const int j  = k & 7;
    const int nt = n >> 4;        // 16-wide N tile
    const int r  = n & 15;
    const int off = (((kk * 32 + nt) * 64) + (q * 16 + r)) * 8 + j;
    Wt[off] = (bf16_t)Wh[id];     // coalesced read, scattered 2B write (one-time)
}

// ---------------------------------------------------------------------------
// K1: e[m] = sum_h tanh( (enc @ W_h)[m][h] + dec_feat[b][h] + cov[m]*W_c[h] ) * v[h]
// MFMA GEMM, M_tile=64 (per block), N=512 (full), K=1024, BK=64.
// 512 threads = 8 waves; wave w owns n in [w*64, w*64+64) (4 n-tiles), all 4 m-tiles.
// ---------------------------------------------------------------------------
__launch_bounds__(512)
__global__ void escore_kernel(const float* __restrict__ enc,   // (M, 1024) fp32
                              const bf16_t* __restrict__ Wt,   // packed W_h bf16
                              const float* __restrict__ decf,  // (B, 512)
                              const float* __restrict__ cov,   // (B, 2048)
                              const float* __restrict__ Wc,    // (512)
                              const float* __restrict__ v,     // (512)
                              float* __restrict__ e_out) {     // (M)
    __shared__ bf16_t Alds[64][72];     // stride 72: 16B-aligned rows, <=2-way bank alias
    __shared__ float red[8][64];

    const int tid  = threadIdx.x;
    const int wave = tid >> 6;
    const int lane = tid & 63;
    const int r = lane & 15, q = lane >> 4;
    const int m0 = blockIdx.x * 64;

    floatx4 acc[4][4];
#pragma unroll
    for (int a = 0; a < 4; ++a)
#pragma unroll
        for (int c = 0; c < 4; ++c) acc[a][c] = (floatx4){0.f, 0.f, 0.f, 0.f};

    const int row0 = tid >> 4;   // 0..31
    const int col4 = tid & 15;   // float4 column

    for (int kk2 = 0; kk2 < 16; ++kk2) {          // K steps of 64
        // ---- stage A tile (64 x 64 fp32 -> bf16 LDS), coalesced 256B rows
        float4 f0 = *(const float4*)&enc[(size_t)(m0 + row0) * K2H + kk2 * 64 + col4 * 4];
        float4 f1 = *(const float4*)&enc[(size_t)(m0 + row0 + 32) * K2H + kk2 * 64 + col4 * 4];
        __syncthreads();   // previous iter's frag reads done
        {
            bf16x4 b0, b1;
            b0.x = (bf16_t)f0.x; b0.y = (bf16_t)f0.y; b0.z = (bf16_t)f0.z; b0.w = (bf16_t)f0.w;
            b1.x = (bf16_t)f1.x; b1.y = (bf16_t)f1.y; b1.z = (bf16_t)f1.z; b1.w = (bf16_t)f1.w;
            *(bf16x4*)&Alds[row0][col4 * 4]      = b0;
            *(bf16x4*)&Alds[row0 + 32][col4 * 4] = b1;
        }
        __syncthreads();
        // ---- compute
#pragma unroll
        for (int ks = 0; ks < 2; ++ks) {
            const int kkg = kk2 * 2 + ks;         // 32-wide K step index
            bf16x8 bfr[4];
#pragma unroll
            for (int ntl = 0; ntl < 4; ++ntl) {
                const int ntg = wave * 4 + ntl;
                bfr[ntl] = *(const bf16x8*)&Wt[(((size_t)(kkg * 32 + ntg)) * 64 + lane) * 8];
            }
#pragma unroll
            for (int mt = 0; mt < 4; ++mt) {
                bf16x8 afr = *(const bf16x8*)&Alds[mt * 16 + r][ks * 32 + q * 8];
#pragma unroll
                for (int ntl = 0; ntl < 4; ++ntl)
                    acc[mt][ntl] = __builtin_amdgcn_mfma_f32_16x16x32_bf16(
                        afr, bfr[ntl], acc[mt][ntl], 0, 0, 0);
            }
        }
    }

    // ---- epilogue: tanh, dot with v, reduce over n
    const int b     = m0 >> 11;       // m0 / 2048
    const int sbase = m0 & 2047;
    float dval[4], wcv[4], vv[4];
#pragma unroll
    for (int ntl = 0; ntl < 4; ++ntl) {
        const int n = wave * 64 + ntl * 16 + r;
        dval[ntl] = decf[b * HDIM + n];
        wcv[ntl]  = Wc[n];
        vv[ntl]   = v[n];
    }
#pragma unroll
    for (int mt = 0; mt < 4; ++mt) {
#pragma unroll
        for (int i = 0; i < 4; ++i) {
            const int mloc = mt * 16 + q * 4 + i;      // C/D row = quad*4 + reg
            const float cm = cov[b * SEQ + sbase + mloc];
            float p = 0.f;
#pragma unroll
            for (int ntl = 0; ntl < 4; ++ntl) {
                float x = acc[mt][ntl][i] + dval[ntl] + cm * wcv[ntl];
                x = fminf(fmaxf(x, -15.f), 15.f);      // clamp: no inf/inf
                float z = __expf(2.f * x);             // tanh = (z-1)/(z+1)
                p += (1.f - 2.f / (z + 1.f)) * vv[ntl];
            }
            // reduce over r (lanes sharing quad hold same row, different n)
#pragma unroll
            for (int off = 1; off < 16; off <<= 1)
                p += __shfl_xor(p, off, 64);
            if (r == 0) red[wave][mloc] = p;
        }
    }
    __syncthreads();
    if (tid < 64) {
        float s = 0.f;
#pragma unroll
        for (int w = 0; w < 8; ++w) s += red[w][tid];
        e_out[(size_t)m0 + tid] = s;
    }
}

// ---------------------------------------------------------------------------
// K2: masked softmax over S per batch row + coverage update.
// ed holds e on entry; overwritten in place with dist.
// ---------------------------------------------------------------------------
__global__ void softmax_kernel(float* ed,                       // e in, dist out
                               const int* __restrict__ mask,
                               const float* __restrict__ cov,
                               float* __restrict__ ncov) {
    const int b = blockIdx.x, tid = threadIdx.x;   // 256 threads
    __shared__ float wred[4];
    float ev[8];
    float mx = -1e30f;
#pragma unroll
    for (int i = 0; i < 8; ++i) {
        const int s = tid + i * 256;
        float e = ed[b * SEQ + s];
        e = (mask[b * SEQ + s] == 0) ? -10000.f : e;
        ev[i] = e;
        mx = fmaxf(mx, e);
    }
#pragma unroll
    for (int off = 32; off; off >>= 1) mx = fmaxf(mx, __shfl_xor(mx, off, 64));
    if ((tid & 63) == 0) wred[tid >> 6] = mx;
    __syncthreads();
    mx = fmaxf(fmaxf(wred[0], wred[1]), fmaxf(wred[2], wred[3]));
    __syncthreads();
    float sum = 0.f;
#pragma unroll
    for (int i = 0; i < 8; ++i) { ev[i] = __expf(ev[i] - mx); sum += ev[i]; }
#pragma unroll
    for (int off = 32; off; off >>= 1) sum += __shfl_xor(sum, off, 64);
    if ((tid & 63) == 0) wred[tid >> 6] = sum;
    __syncthreads();
    sum = wred[0] + wred[1] + wred[2] + wred[3];
    const float inv = 1.f / sum;
#pragma unroll
    for (int i = 0; i < 8; ++i) {
        const int s = tid + i * 256;
        const float d = ev[i] * inv;
        ed[b * SEQ + s]   = d;
        ncov[b * SEQ + s] = cov[b * SEQ + s] + d;
    }
}

// ---------------------------------------------------------------------------
// K3: context[b][k] = sum_s dist[b][s] * enc[b][s][k]. Grid (B, 8 s-chunks).
// ---------------------------------------------------------------------------
__global__ void context_kernel(const float* __restrict__ enc,
                               const float* __restrict__ dist,
                               float* __restrict__ ctx) {
    const int b = blockIdx.x, sc = blockIdx.y, tid = threadIdx.x;  // 256 thr
    __shared__ float wl[256];
    wl[tid] = dist[b * SEQ + sc * 256 + tid];
    __syncthreads();
    float4 a = {0.f, 0.f, 0.f, 0.f};
    const float* base = enc + (size_t)(b * SEQ + sc * 256) * K2H + tid * 4;
#pragma unroll 4
    for (int s = 0; s < 256; ++s) {
        const float w = wl[s];
        float4 xv = *(const float4*)(base + (size_t)s * K2H);
        a.x += w * xv.x; a.y += w * xv.y; a.z += w * xv.z; a.w += w * xv.w;
    }
    float* o = ctx + b * K2H + tid * 4;
    atomicAdd(o + 0, a.x);
    atomicAdd(o + 1, a.y);
    atomicAdd(o + 2, a.z);
    atomicAdd(o + 3, a.w);
}

// ---------------------------------------------------------------------------
extern "C" void kernel_launch(void* const* d_in, const int* in_sizes, int n_in,
                              void* d_out, int out_size, void* d_ws, size_t ws_size,
                              hipStream_t stream) {
    const float* dec  = (const float*)d_in[0];
    const float* enc  = (const float*)d_in[1];
    const int*   mask = (const int*)d_in[2];
    const float* cov  = (const float*)d_in[3];
    const float* Wh   = (const float*)d_in[4];
    const float* Ws   = (const float*)d_in[5];
    const float* bs   = (const float*)d_in[6];
    const float* Wc   = (const float*)d_in[7];
    const float* v    = (const float*)d_in[8];

    float* out  = (float*)d_out;
    float* ctx  = out;                       // (B, 1024)  = 65536
    float* dist = out + BATCH * K2H;         // (B, 2048)  = 131072 (e buffer first)
    float* ncov = dist + BATCH * SEQ;        // (B, 2048)

    bf16_t* Wt   = (bf16_t*)d_ws;                        // 1 MB packed W_h
    float*  decf = (float*)((char*)d_ws + (1 << 20));    // 128 KB dec_feat

    hipMemsetAsync(ctx, 0, BATCH * K2H * sizeof(float), stream);  // for atomics
    pack_wh_kernel<<<2048, 256, 0, stream>>>(Wh, Wt);
    dec_feat_kernel<<<BATCH, 512, 0, stream>>>(dec, Ws, bs, decf);
    escore_kernel<<<MROWS / 64, 512, 0, stream>>>(enc, Wt, decf, cov, Wc, v, dist);
    softmax_kernel<<<BATCH, 256, 0, stream>>>(dist, mask, cov, ncov);
    context_kernel<<<dim3(BATCH, 8), 256, 0, stream>>>(enc, dist, ctx);
}